// Round 14
// baseline (137.387 us; speedup 1.0000x reference)
//
#include <hip/hip_runtime.h>

#define N_NODES 100000
#define N_EDGES 1600000
#define IN_F 256
#define OUT_F 128

// two-level counting sort params
#define NBUCK 391            // ceil(N_NODES / 256): coarse bucket = dst >> 8
#define NCHUNK 256           // edge chunks
#define CHUNK_E (N_EDGES / NCHUNK)  // 6250
#define NSCAN (NBUCK * NCHUNK)      // 100096 count-matrix entries (mult of 16)
#define SCAN_BLK 4096        // elems per scan1 block
#define NSCAN_BLOCKS ((NSCAN + SCAN_BLK - 1) / SCAN_BLK)  // 25

#define GEMM_BM 128
#define GEMM_BLOCKS ((N_NODES + GEMM_BM - 1) / GEMM_BM)   // 782

typedef __attribute__((ext_vector_type(8))) short bf16x8;
typedef __attribute__((ext_vector_type(4))) float f32x4;

__device__ __forceinline__ unsigned short f2bf(float f) {
    unsigned u = __float_as_uint(f);
    unsigned r = u + 0x7fffu + ((u >> 16) & 1u);  // RNE
    return (unsigned short)(r >> 16);
}

// ---------------------------------------------------------------------------
// K1: count (blocks 0..255)  ∥  wtrans (blocks 256..383)
// ---------------------------------------------------------------------------
__global__ __launch_bounds__(256) void count_wtrans_kernel(const int* __restrict__ rowi,
                                                           int* __restrict__ counts,
                                                           const float* __restrict__ w,
                                                           unsigned short* __restrict__ wt) {
    const int tid = threadIdx.x;
    if (blockIdx.x >= NCHUNK) {
        int c = blockIdx.x - NCHUNK;  // 0..127
        wt[c * IN_F + tid] = f2bf(w[tid * OUT_F + c]);
        return;
    }
    __shared__ int hist[NBUCK];
    const int c = blockIdx.x;
    for (int i = tid; i < NBUCK; i += 256) hist[i] = 0;
    __syncthreads();
    const int e0 = c * CHUNK_E;
    for (int i = tid; i < CHUNK_E; i += 256)
        atomicAdd(&hist[rowi[e0 + i] >> 8], 1);
    __syncthreads();
    for (int i = tid; i < NBUCK; i += 256) counts[i * NCHUNK + c] = hist[i];
}

// ---------------------------------------------------------------------------
// K2: scan1 — per-block (4096 elems) exclusive scan in place + block sums.
// ---------------------------------------------------------------------------
__global__ __launch_bounds__(256) void scan1_kernel(int* __restrict__ data,
                                                    int* __restrict__ blocksums,
                                                    int n) {
    __shared__ int sdata[256];
    const int tid = threadIdx.x;
    const int base = blockIdx.x * SCAN_BLK + tid * 16;
    int v[16];
    if (base < n) {
#pragma unroll
        for (int q = 0; q < 4; ++q) {
            int4 t = *reinterpret_cast<const int4*>(&data[base + q * 4]);
            v[q * 4 + 0] = t.x; v[q * 4 + 1] = t.y; v[q * 4 + 2] = t.z; v[q * 4 + 3] = t.w;
        }
    } else {
#pragma unroll
        for (int i = 0; i < 16; ++i) v[i] = 0;
    }
    int pre[16], run = 0;
#pragma unroll
    for (int i = 0; i < 16; ++i) { pre[i] = run; run += v[i]; }
    sdata[tid] = run;
    __syncthreads();
#pragma unroll
    for (int off = 1; off < 256; off <<= 1) {
        int t = (tid >= off) ? sdata[tid - off] : 0;
        __syncthreads();
        sdata[tid] += t;
        __syncthreads();
    }
    int excl = (tid == 0) ? 0 : sdata[tid - 1];
    if (base < n) {
#pragma unroll
        for (int q = 0; q < 4; ++q) {
            int4 t = {excl + pre[q * 4 + 0], excl + pre[q * 4 + 1],
                      excl + pre[q * 4 + 2], excl + pre[q * 4 + 3]};
            *reinterpret_cast<int4*>(&data[base + q * 4]) = t;
        }
    }
    if (tid == 255) blocksums[blockIdx.x] = sdata[255];
}

// ---------------------------------------------------------------------------
// K3: scan2 — single block exclusive scan of nblk (<=256) block sums.
// ---------------------------------------------------------------------------
__global__ __launch_bounds__(256) void scan2_kernel(int* __restrict__ blocksums, int nblk) {
    __shared__ int sdata[256];
    const int tid = threadIdx.x;
    sdata[tid] = (tid < nblk) ? blocksums[tid] : 0;
    __syncthreads();
#pragma unroll
    for (int off = 1; off < 256; off <<= 1) {
        int t = (tid >= off) ? sdata[tid - off] : 0;
        __syncthreads();
        sdata[tid] += t;
        __syncthreads();
    }
    if (tid < nblk) blocksums[tid] = (tid == 0) ? 0 : sdata[tid - 1];
}

// ---------------------------------------------------------------------------
// K4: scatter1 (blocks 0..255)  ∥  gemm (blocks 256..1037), 512 threads.
// gemm: BM=128, 8 waves, each wave owns 16 rows x all 128 cols.
// - wt (64 KB bf16, entire K=256) staged in LDS ONCE, XOR-swizzled.
// - Barrier-free k-loop; ALL 16 A-vector loads hoisted into registers
//   up front (independent, wave-exclusive rows) -> single latency exposure.
// ---------------------------------------------------------------------------
__global__ __launch_bounds__(512, 4) void gemm_scatter_kernel(const float* __restrict__ x,
                                                              const unsigned short* __restrict__ wt,
                                                              unsigned short* __restrict__ support,
                                                              const int* __restrict__ rowi,
                                                              const int* __restrict__ coli,
                                                              const float* __restrict__ val,
                                                              const int* __restrict__ counts,
                                                              const int* __restrict__ blocksums,
                                                              uint2* __restrict__ tmp) {
    __shared__ unsigned short ws[128 * 256];  // 64 KB: [col][swizzled 16B chunk]
    __shared__ int cur[NBUCK];                // scatter path only

    const int tid = threadIdx.x;

    if (blockIdx.x < NCHUNK) {
        // ----- scatter1 (512 threads) -----
        const int c = blockIdx.x;
        for (int i = tid; i < NBUCK; i += 512) {
            int j = i * NCHUNK + c;
            cur[i] = counts[j] + blocksums[j >> 12];
        }
        __syncthreads();
        const int e0 = c * CHUNK_E;
        for (int i = tid; i < CHUNK_E; i += 512) {
            int e = e0 + i;
            int dst = rowi[e];
            int b = dst >> 8;
            int pos = atomicAdd(&cur[b], 1);
            tmp[pos] = make_uint2(((unsigned)(dst & 255) << 17) | (unsigned)coli[e],
                                  __float_as_uint(val[e]));
        }
        return;
    }

    // ----- gemm -----
    const int lane = tid & 63;
    const int wv = tid >> 6;        // wave 0..7 -> rows wv*16..+15
    const int row0 = (blockIdx.x - NCHUNK) * GEMM_BM;
    const int l15 = lane & 15;
    const int kq = lane >> 4;       // k-quarter (frag loads) / row-quad (epilogue)

    // stage whole wt into LDS, swizzled: chunk c of col stored at slot c^(col&7)
#pragma unroll
    for (int it = 0; it < 8; ++it) {
        int ci = it * 512 + tid;          // 16B-chunk index 0..4095
        int col = ci >> 5, ch = ci & 31;  // col 0..127, chunk 0..31
        uint4 v = *reinterpret_cast<const uint4*>(&wt[col * IN_F + ch * 8]);
        int slot = ch ^ (col & 7);
        *reinterpret_cast<uint4*>(&ws[col * 256 + slot * 8]) = v;
    }

    int arow = row0 + wv * 16 + l15;
    if (arow > N_NODES - 1) arow = N_NODES - 1;
    const float* xrow = &x[(size_t)arow * IN_F + kq * 8];

    // hoist ALL A-loads (16 independent f32x4) before the compute loop
    f32x4 a[16];
#pragma unroll
    for (int kt = 0; kt < 8; ++kt) {
        a[2 * kt + 0] = *reinterpret_cast<const f32x4*>(xrow + kt * 32);
        a[2 * kt + 1] = *reinterpret_cast<const f32x4*>(xrow + kt * 32 + 4);
    }

    __syncthreads();  // the ONLY barrier (ws ready)

    f32x4 acc[8];
#pragma unroll
    for (int n = 0; n < 8; ++n) acc[n] = (f32x4){0.f, 0.f, 0.f, 0.f};

#pragma unroll
    for (int kt = 0; kt < 8; ++kt) {
        f32x4 a0 = a[2 * kt + 0];
        f32x4 a1 = a[2 * kt + 1];
        bf16x8 af;
        af[0] = (short)f2bf(a0[0]); af[1] = (short)f2bf(a0[1]);
        af[2] = (short)f2bf(a0[2]); af[3] = (short)f2bf(a0[3]);
        af[4] = (short)f2bf(a1[0]); af[5] = (short)f2bf(a1[1]);
        af[6] = (short)f2bf(a1[2]); af[7] = (short)f2bf(a1[3]);
#pragma unroll
        for (int n = 0; n < 8; ++n) {
            int col = n * 16 + l15;
            int slot = (kt * 4 + kq) ^ (col & 7);
            bf16x8 bfv = *reinterpret_cast<const bf16x8*>(&ws[col * 256 + slot * 8]);
            acc[n] = __builtin_amdgcn_mfma_f32_16x16x32_bf16(af, bfv, acc[n], 0, 0, 0);
        }
    }

    // epilogue: C/D layout col=lane&15, row=(lane>>4)*4+r
#pragma unroll
    for (int r = 0; r < 4; ++r) {
        int row = row0 + wv * 16 + kq * 4 + r;
        if (row < N_NODES) {
#pragma unroll
            for (int n = 0; n < 8; ++n) {
                support[(size_t)row * OUT_F + n * 16 + l15] = f2bf(acc[n][r]);
            }
        }
    }
}

// ---------------------------------------------------------------------------
// K5: fine sort within one 256-node bucket; writes per-node end offsets.
// ---------------------------------------------------------------------------
__global__ __launch_bounds__(256) void fine_kernel(const uint2* __restrict__ tmp,
                                                   const int* __restrict__ counts,
                                                   const int* __restrict__ blocksums,
                                                   uint2* __restrict__ pairs,
                                                   int* __restrict__ offsets) {
    __shared__ int hist[256];
    __shared__ int scanb[256];
    __shared__ int cur[256];
    const int tid = threadIdx.x, b = blockIdx.x;
    int j0 = b * NCHUNK;
    const int start = counts[j0] + blocksums[j0 >> 12];
    int end;
    if (b == NBUCK - 1) end = N_EDGES;
    else {
        int j1 = (b + 1) * NCHUNK;
        end = counts[j1] + blocksums[j1 >> 12];
    }

    hist[tid] = 0;
    __syncthreads();
    for (int i = start + tid; i < end; i += 256)
        atomicAdd(&hist[tmp[i].x >> 17], 1);
    __syncthreads();
    int h = hist[tid];
    scanb[tid] = h;
    __syncthreads();
#pragma unroll
    for (int off = 1; off < 256; off <<= 1) {
        int t = (tid >= off) ? scanb[tid - off] : 0;
        __syncthreads();
        scanb[tid] += t;
        __syncthreads();
    }
    cur[tid] = start + scanb[tid] - h;
    int node = (b << 8) + tid;
    if (node < N_NODES) offsets[node] = start + scanb[tid];
    __syncthreads();
    for (int i = start + tid; i < end; i += 256) {
        uint2 u = tmp[i];
        int dl = u.x >> 17;
        int pos = atomicAdd(&cur[dl], 1);
        pairs[pos] = make_uint2(u.x & 0x1FFFFu, u.y);
    }
}

// ---------------------------------------------------------------------------
// K6: accumulate: one wave64 per node, 4 edge slots x 16 lanes (8 feats each),
// x2 unroll -> 8 gathers in flight per wave. (round-6 proven)
// ---------------------------------------------------------------------------
__global__ __launch_bounds__(256) void accum_kernel(const unsigned short* __restrict__ support,
                                                    const uint2* __restrict__ pairs,
                                                    const int* __restrict__ offsets,
                                                    const float* __restrict__ bias,
                                                    float* __restrict__ out) {
    const int node = blockIdx.x * 4 + (threadIdx.x >> 6);
    const int lane = threadIdx.x & 63;
    const int grp = lane >> 4;   // edge slot 0..3
    const int l16 = lane & 15;   // feats l16*8 .. l16*8+7
    if (node >= N_NODES) return;

    const int start = (node == 0) ? 0 : offsets[node - 1];
    const int end = offsets[node];

    float acc[8];
#pragma unroll
    for (int t = 0; t < 8; ++t) acc[t] = 0.f;

    int j = start + grp;
    for (; j + 4 < end; j += 8) {
        uint2 p0 = pairs[j];
        uint2 p1 = pairs[j + 4];
        uint4 s0 = *reinterpret_cast<const uint4*>(&support[(size_t)p0.x * OUT_F + l16 * 8]);
        uint4 s1 = *reinterpret_cast<const uint4*>(&support[(size_t)p1.x * OUT_F + l16 * 8]);
        float v0 = __uint_as_float(p0.y);
        float v1 = __uint_as_float(p1.y);
        unsigned u0[4] = {s0.x, s0.y, s0.z, s0.w};
        unsigned u1[4] = {s1.x, s1.y, s1.z, s1.w};
#pragma unroll
        for (int q = 0; q < 4; ++q) {
            acc[2 * q + 0] += __uint_as_float(u0[q] << 16) * v0;
            acc[2 * q + 1] += __uint_as_float(u0[q] & 0xffff0000u) * v0;
            acc[2 * q + 0] += __uint_as_float(u1[q] << 16) * v1;
            acc[2 * q + 1] += __uint_as_float(u1[q] & 0xffff0000u) * v1;
        }
    }
    for (; j < end; j += 4) {
        uint2 p0 = pairs[j];
        uint4 s0 = *reinterpret_cast<const uint4*>(&support[(size_t)p0.x * OUT_F + l16 * 8]);
        float v0 = __uint_as_float(p0.y);
        unsigned u0[4] = {s0.x, s0.y, s0.z, s0.w};
#pragma unroll
        for (int q = 0; q < 4; ++q) {
            acc[2 * q + 0] += __uint_as_float(u0[q] << 16) * v0;
            acc[2 * q + 1] += __uint_as_float(u0[q] & 0xffff0000u) * v0;
        }
    }

#pragma unroll
    for (int t = 0; t < 8; ++t) {
        acc[t] += __shfl_xor(acc[t], 16);
        acc[t] += __shfl_xor(acc[t], 32);
    }

    if (grp == 0) {
        float4 b0 = *reinterpret_cast<const float4*>(&bias[l16 * 8]);
        float4 b1 = *reinterpret_cast<const float4*>(&bias[l16 * 8 + 4]);
        f32x4 o0 = {acc[0] + b0.x, acc[1] + b0.y, acc[2] + b0.z, acc[3] + b0.w};
        f32x4 o1 = {acc[4] + b1.x, acc[5] + b1.y, acc[6] + b1.z, acc[7] + b1.w};
        f32x4* op = reinterpret_cast<f32x4*>(&out[(size_t)node * OUT_F + l16 * 8]);
        __builtin_nontemporal_store(o0, op);
        __builtin_nontemporal_store(o1, op + 1);
    }
}

extern "C" void kernel_launch(void* const* d_in, const int* in_sizes, int n_in,
                              void* d_out, int out_size, void* d_ws, size_t ws_size,
                              hipStream_t stream) {
    const float* x       = (const float*)d_in[0];
    const float* weight  = (const float*)d_in[1];
    const float* bias    = (const float*)d_in[2];
    const float* adj_val = (const float*)d_in[3];
    const int*   adj_row = (const int*)d_in[4];
    const int*   adj_col = (const int*)d_in[5];
    float* out = (float*)d_out;

    unsigned short* support = (unsigned short*)d_ws;
    unsigned short* wt = support + (size_t)N_NODES * OUT_F;
    int* counts = (int*)(wt + IN_F * OUT_F);
    int* blocksums = counts + NSCAN;
    int* offsets = blocksums + 32;
    uint2* tmp = (uint2*)(offsets + 100000);
    uint2* pairs = tmp + N_EDGES;

    // K1: count ∥ wtrans
    count_wtrans_kernel<<<NCHUNK + OUT_F, 256, 0, stream>>>(adj_row, counts, weight, wt);
    // K2/K3: scan
    scan1_kernel<<<NSCAN_BLOCKS, 256, 0, stream>>>(counts, blocksums, NSCAN);
    scan2_kernel<<<1, 256, 0, stream>>>(blocksums, NSCAN_BLOCKS);
    // K4: scatter1 ∥ gemm (barrier-free k-loop, hoisted A-loads)
    gemm_scatter_kernel<<<NCHUNK + GEMM_BLOCKS, 512, 0, stream>>>(
        x, wt, support, adj_row, adj_col, adj_val, counts, blocksums, tmp);
    // K5: fine sort per bucket
    fine_kernel<<<NBUCK, 256, 0, stream>>>(tmp, counts, blocksums, pairs, offsets);
    // K6: accumulate per destination node
    accum_kernel<<<(N_NODES + 3) / 4, 256, 0, stream>>>(support, pairs, offsets, bias, out);
}

// Round 15
// 127.529 us; speedup vs baseline: 1.0773x; 1.0773x over previous
//
#include <hip/hip_runtime.h>

#define N_NODES 100000
#define N_EDGES 1600000
#define IN_F 256
#define OUT_F 128

// counting sort params: 64-node buckets
#define NBUCK 1563           // ceil(N_NODES / 64): bucket = dst >> 6
#define NCHUNK 256           // edge chunks
#define CHUNK_E (N_EDGES / NCHUNK)  // 6250
#define NSCAN (NBUCK * NCHUNK)      // 400128 (mult of 16)
#define SCAN_BLK 4096
#define NSCAN_BLOCKS ((NSCAN + SCAN_BLK - 1) / SCAN_BLK)  // 98

#define GEMM_BM 128
#define GEMM_BLOCKS ((N_NODES + GEMM_BM - 1) / GEMM_BM)   // 782

#define FBUCK 64             // nodes per bucket
#define CAP 1664             // LDS pair slots (mean 1024, std 32 -> 20 sigma)

typedef __attribute__((ext_vector_type(8))) short bf16x8;
typedef __attribute__((ext_vector_type(4))) float f32x4;

__device__ __forceinline__ unsigned short f2bf(float f) {
    unsigned u = __float_as_uint(f);
    unsigned r = u + 0x7fffu + ((u >> 16) & 1u);  // RNE
    return (unsigned short)(r >> 16);
}

// ---------------------------------------------------------------------------
// K1: count (blocks 0..255)  ∥  wtrans (blocks 256..383)
// ---------------------------------------------------------------------------
__global__ __launch_bounds__(256) void count_wtrans_kernel(const int* __restrict__ rowi,
                                                           int* __restrict__ counts,
                                                           const float* __restrict__ w,
                                                           unsigned short* __restrict__ wt) {
    const int tid = threadIdx.x;
    if (blockIdx.x >= NCHUNK) {
        int c = blockIdx.x - NCHUNK;  // 0..127
        wt[c * IN_F + tid] = f2bf(w[tid * OUT_F + c]);
        return;
    }
    __shared__ int hist[NBUCK];
    const int c = blockIdx.x;
    for (int i = tid; i < NBUCK; i += 256) hist[i] = 0;
    __syncthreads();
    const int e0 = c * CHUNK_E;
    for (int i = tid; i < CHUNK_E; i += 256)
        atomicAdd(&hist[rowi[e0 + i] >> 6], 1);
    __syncthreads();
    for (int i = tid; i < NBUCK; i += 256) counts[i * NCHUNK + c] = hist[i];
}

// ---------------------------------------------------------------------------
// K2: scan1 — per-block (4096 elems) exclusive scan in place + block sums.
// ---------------------------------------------------------------------------
__global__ __launch_bounds__(256) void scan1_kernel(int* __restrict__ data,
                                                    int* __restrict__ blocksums,
                                                    int n) {
    __shared__ int sdata[256];
    const int tid = threadIdx.x;
    const int base = blockIdx.x * SCAN_BLK + tid * 16;
    int v[16];
    if (base < n) {
#pragma unroll
        for (int q = 0; q < 4; ++q) {
            int4 t = *reinterpret_cast<const int4*>(&data[base + q * 4]);
            v[q * 4 + 0] = t.x; v[q * 4 + 1] = t.y; v[q * 4 + 2] = t.z; v[q * 4 + 3] = t.w;
        }
    } else {
#pragma unroll
        for (int i = 0; i < 16; ++i) v[i] = 0;
    }
    int pre[16], run = 0;
#pragma unroll
    for (int i = 0; i < 16; ++i) { pre[i] = run; run += v[i]; }
    sdata[tid] = run;
    __syncthreads();
#pragma unroll
    for (int off = 1; off < 256; off <<= 1) {
        int t = (tid >= off) ? sdata[tid - off] : 0;
        __syncthreads();
        sdata[tid] += t;
        __syncthreads();
    }
    int excl = (tid == 0) ? 0 : sdata[tid - 1];
    if (base < n) {
#pragma unroll
        for (int q = 0; q < 4; ++q) {
            int4 t = {excl + pre[q * 4 + 0], excl + pre[q * 4 + 1],
                      excl + pre[q * 4 + 2], excl + pre[q * 4 + 3]};
            *reinterpret_cast<int4*>(&data[base + q * 4]) = t;
        }
    }
    if (tid == 255) blocksums[blockIdx.x] = sdata[255];
}

// ---------------------------------------------------------------------------
// K3: scan2 — single block exclusive scan of nblk (<=256) block sums.
// ---------------------------------------------------------------------------
__global__ __launch_bounds__(256) void scan2_kernel(int* __restrict__ blocksums, int nblk) {
    __shared__ int sdata[256];
    const int tid = threadIdx.x;
    sdata[tid] = (tid < nblk) ? blocksums[tid] : 0;
    __syncthreads();
#pragma unroll
    for (int off = 1; off < 256; off <<= 1) {
        int t = (tid >= off) ? sdata[tid - off] : 0;
        __syncthreads();
        sdata[tid] += t;
        __syncthreads();
    }
    if (tid < nblk) blocksums[tid] = (tid == 0) ? 0 : sdata[tid - 1];
}

// ---------------------------------------------------------------------------
// K4: scatter1 (blocks 0..255)  ∥  gemm (blocks 256..1037), 512 threads.
// gemm: BM=128, 8 waves; wt (64 KB, whole K) resident in LDS, XOR-swizzled;
// barrier-free k-loop (R13 proven). scatter encodes (dst&63)<<17 | col.
// ---------------------------------------------------------------------------
__global__ __launch_bounds__(512, 4) void gemm_scatter_kernel(const float* __restrict__ x,
                                                              const unsigned short* __restrict__ wt,
                                                              unsigned short* __restrict__ support,
                                                              const int* __restrict__ rowi,
                                                              const int* __restrict__ coli,
                                                              const float* __restrict__ val,
                                                              const int* __restrict__ counts,
                                                              const int* __restrict__ blocksums,
                                                              uint2* __restrict__ tmp) {
    __shared__ unsigned short ws[128 * 256];  // 64 KB
    __shared__ int cur[NBUCK];                // scatter path only (6.3 KB)

    const int tid = threadIdx.x;

    if (blockIdx.x < NCHUNK) {
        // ----- scatter1 (512 threads) -----
        const int c = blockIdx.x;
        for (int i = tid; i < NBUCK; i += 512) {
            int j = i * NCHUNK + c;
            cur[i] = counts[j] + blocksums[j >> 12];
        }
        __syncthreads();
        const int e0 = c * CHUNK_E;
        for (int i = tid; i < CHUNK_E; i += 512) {
            int e = e0 + i;
            int dst = rowi[e];
            int b = dst >> 6;
            int pos = atomicAdd(&cur[b], 1);
            tmp[pos] = make_uint2(((unsigned)(dst & 63) << 17) | (unsigned)coli[e],
                                  __float_as_uint(val[e]));
        }
        return;
    }

    // ----- gemm -----
    const int lane = tid & 63;
    const int wv = tid >> 6;
    const int row0 = (blockIdx.x - NCHUNK) * GEMM_BM;
    const int l15 = lane & 15;
    const int kq = lane >> 4;

#pragma unroll
    for (int it = 0; it < 8; ++it) {
        int ci = it * 512 + tid;
        int col = ci >> 5, ch = ci & 31;
        uint4 v = *reinterpret_cast<const uint4*>(&wt[col * IN_F + ch * 8]);
        int slot = ch ^ (col & 7);
        *reinterpret_cast<uint4*>(&ws[col * 256 + slot * 8]) = v;
    }
    __syncthreads();  // the ONLY barrier

    int arow = row0 + wv * 16 + l15;
    if (arow > N_NODES - 1) arow = N_NODES - 1;
    const float* xrow = &x[(size_t)arow * IN_F + kq * 8];

    f32x4 acc[8];
#pragma unroll
    for (int n = 0; n < 8; ++n) acc[n] = (f32x4){0.f, 0.f, 0.f, 0.f};

#pragma unroll
    for (int kt = 0; kt < 8; ++kt) {
        f32x4 a0 = *reinterpret_cast<const f32x4*>(xrow + kt * 32);
        f32x4 a1 = *reinterpret_cast<const f32x4*>(xrow + kt * 32 + 4);
        bf16x8 af;
        af[0] = (short)f2bf(a0[0]); af[1] = (short)f2bf(a0[1]);
        af[2] = (short)f2bf(a0[2]); af[3] = (short)f2bf(a0[3]);
        af[4] = (short)f2bf(a1[0]); af[5] = (short)f2bf(a1[1]);
        af[6] = (short)f2bf(a1[2]); af[7] = (short)f2bf(a1[3]);
#pragma unroll
        for (int n = 0; n < 8; ++n) {
            int col = n * 16 + l15;
            int slot = (kt * 4 + kq) ^ (col & 7);
            bf16x8 bfv = *reinterpret_cast<const bf16x8*>(&ws[col * 256 + slot * 8]);
            acc[n] = __builtin_amdgcn_mfma_f32_16x16x32_bf16(af, bfv, acc[n], 0, 0, 0);
        }
    }

#pragma unroll
    for (int r = 0; r < 4; ++r) {
        int row = row0 + wv * 16 + kq * 4 + r;
        if (row < N_NODES) {
#pragma unroll
            for (int n = 0; n < 8; ++n) {
                support[(size_t)row * OUT_F + n * 16 + l15] = f2bf(acc[n][r]);
            }
        }
    }
}

// ---------------------------------------------------------------------------
// K5: fused fine-sort + accumulate, one block per 64-node bucket.
// Sorts the bucket's ~1024 edges into LDS (per-node grouped), then the proven
// accum structure (wave per node, 4 edge slots x 16 lanes, x2 unroll) reads
// pairs from LDS. No global pairs/offsets round trip.
// ---------------------------------------------------------------------------
__global__ __launch_bounds__(256) void fine_accum_kernel(const unsigned short* __restrict__ support,
                                                         const uint2* __restrict__ tmp,
                                                         const int* __restrict__ counts,
                                                         const int* __restrict__ blocksums,
                                                         const float* __restrict__ bias,
                                                         float* __restrict__ out) {
    __shared__ uint2 plds[CAP];    // 13.3 KB sorted pairs
    __shared__ int hist[FBUCK];
    __shared__ int scanb[FBUCK];
    __shared__ int cur[FBUCK];

    const int tid = threadIdx.x, b = blockIdx.x;
    int j0 = b * NCHUNK;
    const int start = counts[j0] + blocksums[j0 >> 12];
    int end;
    if (b == NBUCK - 1) end = N_EDGES;
    else {
        int j1 = (b + 1) * NCHUNK;
        end = counts[j1] + blocksums[j1 >> 12];
    }

    if (tid < FBUCK) hist[tid] = 0;
    __syncthreads();
    for (int i = start + tid; i < end; i += 256)
        atomicAdd(&hist[tmp[i].x >> 17], 1);
    __syncthreads();
    if (tid < FBUCK) scanb[tid] = hist[tid];
    __syncthreads();
#pragma unroll
    for (int off = 1; off < FBUCK; off <<= 1) {
        int t = (tid < FBUCK && tid >= off) ? scanb[tid - off] : 0;
        __syncthreads();
        if (tid < FBUCK) scanb[tid] += t;
        __syncthreads();
    }
    if (tid < FBUCK) cur[tid] = scanb[tid] - hist[tid];  // exclusive starts
    __syncthreads();
    for (int i = start + tid; i < end; i += 256) {
        uint2 u = tmp[i];
        int dl = u.x >> 17;
        int pos = atomicAdd(&cur[dl], 1);
        plds[pos] = make_uint2(u.x & 0x1FFFFu, u.y);
    }
    __syncthreads();

    // accum: 4 waves x 16 nodes each
    const int lane = tid & 63;
    const int wv = tid >> 6;
    const int grp = lane >> 4;   // edge slot 0..3
    const int l16 = lane & 15;   // feats l16*8 .. +7

    float4 b0 = *reinterpret_cast<const float4*>(&bias[l16 * 8]);
    float4 b1 = *reinterpret_cast<const float4*>(&bias[l16 * 8 + 4]);

    for (int ni = 0; ni < 16; ++ni) {
        const int dl = wv * 16 + ni;
        const int node = b * FBUCK + dl;
        if (node >= N_NODES) break;
        const int s = (dl == 0) ? 0 : scanb[dl - 1];
        const int e = scanb[dl];

        float acc[8];
#pragma unroll
        for (int t = 0; t < 8; ++t) acc[t] = 0.f;

        int j = s + grp;
        for (; j + 4 < e; j += 8) {
            uint2 p0 = plds[j];
            uint2 p1 = plds[j + 4];
            uint4 s0 = *reinterpret_cast<const uint4*>(&support[(size_t)p0.x * OUT_F + l16 * 8]);
            uint4 s1 = *reinterpret_cast<const uint4*>(&support[(size_t)p1.x * OUT_F + l16 * 8]);
            float v0 = __uint_as_float(p0.y);
            float v1 = __uint_as_float(p1.y);
            unsigned u0[4] = {s0.x, s0.y, s0.z, s0.w};
            unsigned u1[4] = {s1.x, s1.y, s1.z, s1.w};
#pragma unroll
            for (int q = 0; q < 4; ++q) {
                acc[2 * q + 0] += __uint_as_float(u0[q] << 16) * v0;
                acc[2 * q + 1] += __uint_as_float(u0[q] & 0xffff0000u) * v0;
                acc[2 * q + 0] += __uint_as_float(u1[q] << 16) * v1;
                acc[2 * q + 1] += __uint_as_float(u1[q] & 0xffff0000u) * v1;
            }
        }
        for (; j < e; j += 4) {
            uint2 p0 = plds[j];
            uint4 s0 = *reinterpret_cast<const uint4*>(&support[(size_t)p0.x * OUT_F + l16 * 8]);
            float v0 = __uint_as_float(p0.y);
            unsigned u0[4] = {s0.x, s0.y, s0.z, s0.w};
#pragma unroll
            for (int q = 0; q < 4; ++q) {
                acc[2 * q + 0] += __uint_as_float(u0[q] << 16) * v0;
                acc[2 * q + 1] += __uint_as_float(u0[q] & 0xffff0000u) * v0;
            }
        }

#pragma unroll
        for (int t = 0; t < 8; ++t) {
            acc[t] += __shfl_xor(acc[t], 16);
            acc[t] += __shfl_xor(acc[t], 32);
        }

        if (grp == 0) {
            f32x4 o0 = {acc[0] + b0.x, acc[1] + b0.y, acc[2] + b0.z, acc[3] + b0.w};
            f32x4 o1 = {acc[4] + b1.x, acc[5] + b1.y, acc[6] + b1.z, acc[7] + b1.w};
            f32x4* op = reinterpret_cast<f32x4*>(&out[(size_t)node * OUT_F + l16 * 8]);
            __builtin_nontemporal_store(o0, op);
            __builtin_nontemporal_store(o1, op + 1);
        }
    }
}

extern "C" void kernel_launch(void* const* d_in, const int* in_sizes, int n_in,
                              void* d_out, int out_size, void* d_ws, size_t ws_size,
                              hipStream_t stream) {
    const float* x       = (const float*)d_in[0];
    const float* weight  = (const float*)d_in[1];
    const float* bias    = (const float*)d_in[2];
    const float* adj_val = (const float*)d_in[3];
    const int*   adj_row = (const int*)d_in[4];
    const int*   adj_col = (const int*)d_in[5];
    float* out = (float*)d_out;

    // workspace (~40 MB):
    //   support : 12.8M ushort (25.6 MB)
    //   wt      : 32768 ushort
    //   counts  : 400128 int (1.6 MB)
    //   blocksums: 128 int
    //   tmp     : 1.6M uint2 (12.8 MB)
    unsigned short* support = (unsigned short*)d_ws;
    unsigned short* wt = support + (size_t)N_NODES * OUT_F;
    int* counts = (int*)(wt + IN_F * OUT_F);
    int* blocksums = counts + NSCAN;
    uint2* tmp = (uint2*)(blocksums + 128);  // 400128+128 ints = even -> 8B ok

    // K1: count ∥ wtrans
    count_wtrans_kernel<<<NCHUNK + OUT_F, 256, 0, stream>>>(adj_row, counts, weight, wt);
    // K2/K3: scan
    scan1_kernel<<<NSCAN_BLOCKS, 256, 0, stream>>>(counts, blocksums, NSCAN);
    scan2_kernel<<<1, 256, 0, stream>>>(blocksums, NSCAN_BLOCKS);
    // K4: scatter1 ∥ gemm
    gemm_scatter_kernel<<<NCHUNK + GEMM_BLOCKS, 512, 0, stream>>>(
        x, wt, support, adj_row, adj_col, adj_val, counts, blocksums, tmp);
    // K5: fused fine-sort + accumulate per 64-node bucket
    fine_accum_kernel<<<NBUCK, 256, 0, stream>>>(support, tmp, counts, blocksums, bias, out);
}

// Round 16
// 115.397 us; speedup vs baseline: 1.1906x; 1.1051x over previous
//
#include <hip/hip_runtime.h>

#define N_NODES 100000
#define N_EDGES 1600000
#define IN_F 256
#define OUT_F 128

#define NBUCK 1563           // ceil(N_NODES / 64): bucket = dst >> 6
#define FBUCK 64             // nodes per bucket
#define CAP 1664             // slots per bucket region (mean 1024, 20 sigma)

#define SORT_CHUNKS 128
#define CHUNK_E (N_EDGES / SORT_CHUNKS)  // 12500

#define GEMM_BM 128
#define GEMM_BLOCKS ((N_NODES + GEMM_BM - 1) / GEMM_BM)   // 782

typedef __attribute__((ext_vector_type(8))) short bf16x8;
typedef __attribute__((ext_vector_type(4))) float f32x4;

__device__ __forceinline__ unsigned short f2bf(float f) {
    unsigned u = __float_as_uint(f);
    unsigned r = u + 0x7fffu + ((u >> 16) & 1u);  // RNE
    return (unsigned short)(r >> 16);
}

// ---------------------------------------------------------------------------
// K1: wtrans (blocks 0..127) + zero cursor (blocks 128..134)
// ---------------------------------------------------------------------------
__global__ __launch_bounds__(256) void wz_kernel(const float* __restrict__ w,
                                                 unsigned short* __restrict__ wt,
                                                 int* __restrict__ cursor) {
    const int tid = threadIdx.x;
    if (blockIdx.x < 128) {
        int c = blockIdx.x;
        wt[c * IN_F + tid] = f2bf(w[tid * OUT_F + c]);
    } else {
        int i = (blockIdx.x - 128) * 256 + tid;
        if (i < NBUCK) cursor[i] = 0;
    }
}

// ---------------------------------------------------------------------------
// K2: sort (blocks 0..127)  ∥  gemm (blocks 128..909), 512 threads.
//
// sort: per-chunk LDS histogram -> one global atomicAdd per (chunk,bucket)
// reserves a contiguous range in tmp[b*CAP ..] -> direct scatter. Runs of
// ~8 edges per bucket per chunk stay L2-resident and write-combine.
//
// gemm: BM=128, 8 waves; wt (64 KB, whole K=256) resident in LDS,
// XOR-swizzled; barrier-free k-loop (R13/R15 proven).
// ---------------------------------------------------------------------------
__global__ __launch_bounds__(512, 4) void gemm_sort_kernel(const float* __restrict__ x,
                                                           const unsigned short* __restrict__ wt,
                                                           unsigned short* __restrict__ support,
                                                           const int* __restrict__ rowi,
                                                           const int* __restrict__ coli,
                                                           const float* __restrict__ val,
                                                           int* __restrict__ cursor,
                                                           uint2* __restrict__ tmp) {
    __shared__ unsigned short ws[128 * 256];  // 64 KB (gemm path)
    __shared__ int bh[NBUCK];                 // 6.3 KB (sort path)

    const int tid = threadIdx.x;

    if (blockIdx.x < SORT_CHUNKS) {
        // ----- sort chunk -----
        const int c = blockIdx.x;
        for (int i = tid; i < NBUCK; i += 512) bh[i] = 0;
        __syncthreads();
        const int e0 = c * CHUNK_E;
        for (int i = tid; i < CHUNK_E; i += 512)
            atomicAdd(&bh[rowi[e0 + i] >> 6], 1);
        __syncthreads();
        for (int i = tid; i < NBUCK; i += 512) {
            int n = bh[i];
            bh[i] = n ? atomicAdd(&cursor[i], n) : 0;
        }
        __syncthreads();
        for (int i = tid; i < CHUNK_E; i += 512) {
            int e = e0 + i;
            int dst = rowi[e];
            int b = dst >> 6;
            int pos = atomicAdd(&bh[b], 1);
            tmp[(size_t)b * CAP + pos] =
                make_uint2(((unsigned)(dst & 63) << 17) | (unsigned)coli[e],
                           __float_as_uint(val[e]));
        }
        return;
    }

    // ----- gemm -----
    const int lane = tid & 63;
    const int wv = tid >> 6;
    const int row0 = (blockIdx.x - SORT_CHUNKS) * GEMM_BM;
    const int l15 = lane & 15;
    const int kq = lane >> 4;

#pragma unroll
    for (int it = 0; it < 8; ++it) {
        int ci = it * 512 + tid;
        int col = ci >> 5, ch = ci & 31;
        uint4 v = *reinterpret_cast<const uint4*>(&wt[col * IN_F + ch * 8]);
        int slot = ch ^ (col & 7);
        *reinterpret_cast<uint4*>(&ws[col * 256 + slot * 8]) = v;
    }
    __syncthreads();  // the ONLY barrier

    int arow = row0 + wv * 16 + l15;
    if (arow > N_NODES - 1) arow = N_NODES - 1;
    const float* xrow = &x[(size_t)arow * IN_F + kq * 8];

    f32x4 acc[8];
#pragma unroll
    for (int n = 0; n < 8; ++n) acc[n] = (f32x4){0.f, 0.f, 0.f, 0.f};

#pragma unroll
    for (int kt = 0; kt < 8; ++kt) {
        f32x4 a0 = *reinterpret_cast<const f32x4*>(xrow + kt * 32);
        f32x4 a1 = *reinterpret_cast<const f32x4*>(xrow + kt * 32 + 4);
        bf16x8 af;
        af[0] = (short)f2bf(a0[0]); af[1] = (short)f2bf(a0[1]);
        af[2] = (short)f2bf(a0[2]); af[3] = (short)f2bf(a0[3]);
        af[4] = (short)f2bf(a1[0]); af[5] = (short)f2bf(a1[1]);
        af[6] = (short)f2bf(a1[2]); af[7] = (short)f2bf(a1[3]);
#pragma unroll
        for (int n = 0; n < 8; ++n) {
            int col = n * 16 + l15;
            int slot = (kt * 4 + kq) ^ (col & 7);
            bf16x8 bfv = *reinterpret_cast<const bf16x8*>(&ws[col * 256 + slot * 8]);
            acc[n] = __builtin_amdgcn_mfma_f32_16x16x32_bf16(af, bfv, acc[n], 0, 0, 0);
        }
    }

#pragma unroll
    for (int r = 0; r < 4; ++r) {
        int row = row0 + wv * 16 + kq * 4 + r;
        if (row < N_NODES) {
#pragma unroll
            for (int n = 0; n < 8; ++n) {
                support[(size_t)row * OUT_F + n * 16 + l15] = f2bf(acc[n][r]);
            }
        }
    }
}

// ---------------------------------------------------------------------------
// K3: fused fine-sort + accumulate, one block per 64-node bucket.
// Bucket b's edges live at tmp[b*CAP .. b*CAP+cursor[b]). Sort them into LDS
// grouped per node, then the proven accum (wave per node, 4 edge slots x 16
// lanes, x2 unroll) reads pairs from LDS.
// ---------------------------------------------------------------------------
__global__ __launch_bounds__(256) void fine_accum_kernel(const unsigned short* __restrict__ support,
                                                         const uint2* __restrict__ tmp,
                                                         const int* __restrict__ cursor,
                                                         const float* __restrict__ bias,
                                                         float* __restrict__ out) {
    __shared__ uint2 plds[CAP];    // 13.3 KB sorted pairs
    __shared__ int hist[FBUCK];
    __shared__ int scanb[FBUCK];
    __shared__ int cur[FBUCK];

    const int tid = threadIdx.x, b = blockIdx.x;
    const int cnt = cursor[b];
    const size_t base = (size_t)b * CAP;

    if (tid < FBUCK) hist[tid] = 0;
    __syncthreads();
    for (int i = tid; i < cnt; i += 256)
        atomicAdd(&hist[tmp[base + i].x >> 17], 1);
    __syncthreads();
    if (tid < FBUCK) scanb[tid] = hist[tid];
    __syncthreads();
#pragma unroll
    for (int off = 1; off < FBUCK; off <<= 1) {
        int t = (tid < FBUCK && tid >= off) ? scanb[tid - off] : 0;
        __syncthreads();
        if (tid < FBUCK) scanb[tid] += t;
        __syncthreads();
    }
    if (tid < FBUCK) cur[tid] = scanb[tid] - hist[tid];  // exclusive starts
    __syncthreads();
    for (int i = tid; i < cnt; i += 256) {
        uint2 u = tmp[base + i];
        int dl = u.x >> 17;
        int pos = atomicAdd(&cur[dl], 1);
        plds[pos] = make_uint2(u.x & 0x1FFFFu, u.y);
    }
    __syncthreads();

    // accum: 4 waves x 16 nodes each
    const int lane = tid & 63;
    const int wv = tid >> 6;
    const int grp = lane >> 4;   // edge slot 0..3
    const int l16 = lane & 15;   // feats l16*8 .. +7

    float4 b0 = *reinterpret_cast<const float4*>(&bias[l16 * 8]);
    float4 b1 = *reinterpret_cast<const float4*>(&bias[l16 * 8 + 4]);

    for (int ni = 0; ni < 16; ++ni) {
        const int dl = wv * 16 + ni;
        const int node = b * FBUCK + dl;
        if (node >= N_NODES) break;
        const int s = (dl == 0) ? 0 : scanb[dl - 1];
        const int e = scanb[dl];

        float acc[8];
#pragma unroll
        for (int t = 0; t < 8; ++t) acc[t] = 0.f;

        int j = s + grp;
        for (; j + 4 < e; j += 8) {
            uint2 p0 = plds[j];
            uint2 p1 = plds[j + 4];
            uint4 s0 = *reinterpret_cast<const uint4*>(&support[(size_t)p0.x * OUT_F + l16 * 8]);
            uint4 s1 = *reinterpret_cast<const uint4*>(&support[(size_t)p1.x * OUT_F + l16 * 8]);
            float v0 = __uint_as_float(p0.y);
            float v1 = __uint_as_float(p1.y);
            unsigned u0[4] = {s0.x, s0.y, s0.z, s0.w};
            unsigned u1[4] = {s1.x, s1.y, s1.z, s1.w};
#pragma unroll
            for (int q = 0; q < 4; ++q) {
                acc[2 * q + 0] += __uint_as_float(u0[q] << 16) * v0;
                acc[2 * q + 1] += __uint_as_float(u0[q] & 0xffff0000u) * v0;
                acc[2 * q + 0] += __uint_as_float(u1[q] << 16) * v1;
                acc[2 * q + 1] += __uint_as_float(u1[q] & 0xffff0000u) * v1;
            }
        }
        for (; j < e; j += 4) {
            uint2 p0 = plds[j];
            uint4 s0 = *reinterpret_cast<const uint4*>(&support[(size_t)p0.x * OUT_F + l16 * 8]);
            float v0 = __uint_as_float(p0.y);
            unsigned u0[4] = {s0.x, s0.y, s0.z, s0.w};
#pragma unroll
            for (int q = 0; q < 4; ++q) {
                acc[2 * q + 0] += __uint_as_float(u0[q] << 16) * v0;
                acc[2 * q + 1] += __uint_as_float(u0[q] & 0xffff0000u) * v0;
            }
        }

#pragma unroll
        for (int t = 0; t < 8; ++t) {
            acc[t] += __shfl_xor(acc[t], 16);
            acc[t] += __shfl_xor(acc[t], 32);
        }

        if (grp == 0) {
            f32x4 o0 = {acc[0] + b0.x, acc[1] + b0.y, acc[2] + b0.z, acc[3] + b0.w};
            f32x4 o1 = {acc[4] + b1.x, acc[5] + b1.y, acc[6] + b1.z, acc[7] + b1.w};
            f32x4* op = reinterpret_cast<f32x4*>(&out[(size_t)node * OUT_F + l16 * 8]);
            __builtin_nontemporal_store(o0, op);
            __builtin_nontemporal_store(o1, op + 1);
        }
    }
}

extern "C" void kernel_launch(void* const* d_in, const int* in_sizes, int n_in,
                              void* d_out, int out_size, void* d_ws, size_t ws_size,
                              hipStream_t stream) {
    const float* x       = (const float*)d_in[0];
    const float* weight  = (const float*)d_in[1];
    const float* bias    = (const float*)d_in[2];
    const float* adj_val = (const float*)d_in[3];
    const int*   adj_row = (const int*)d_in[4];
    const int*   adj_col = (const int*)d_in[5];
    float* out = (float*)d_out;

    // workspace (~47 MB):
    //   support : 12.8M ushort (25.6 MB)
    //   wt      : 32768 ushort (64 KB)
    //   cursor  : 1564 int
    //   tmp     : NBUCK*CAP uint2 (20.8 MB)
    unsigned short* support = (unsigned short*)d_ws;
    unsigned short* wt = support + (size_t)N_NODES * OUT_F;
    int* cursor = (int*)(wt + IN_F * OUT_F);
    uint2* tmp = (uint2*)(cursor + 1564);

    // K1: weight transpose + zero bucket cursors
    wz_kernel<<<128 + 7, 256, 0, stream>>>(weight, wt, cursor);
    // K2: sort ∥ gemm
    gemm_sort_kernel<<<SORT_CHUNKS + GEMM_BLOCKS, 512, 0, stream>>>(
        x, wt, support, adj_row, adj_col, adj_val, cursor, tmp);
    // K3: fused fine-sort + accumulate per 64-node bucket
    fine_accum_kernel<<<NBUCK, 256, 0, stream>>>(support, tmp, cursor, bias, out);
}